// Round 9
// baseline (478.753 us; speedup 1.0000x reference)
//
#include <hip/hip_runtime.h>

#define HID 64
#define NGRAPHS 64
#define LIN_NODES 64

// ---------------- degree count + ticket ----------------
// Plain device-scope atomics (R3: address-spreading null; R4: XCD-scope null ->
// flat ~26G/s memory-side cost per atomic is the floor). In-degree atomic's
// return value = edge's slot within its dst node -> k_fill needs no atomics.
__global__ void k_deg(const int* __restrict__ src, const int* __restrict__ dst,
                      int* __restrict__ dgO, int* __restrict__ dgI,
                      unsigned short* __restrict__ gt, int E) {
  int e = blockIdx.x * 256 + threadIdx.x;
  if (e >= E) return;
  atomicAdd(&dgO[src[e]], 1);
  int t = atomicAdd(&dgI[dst[e]], 1);
  gt[e] = (unsigned short)t;   // in-degree << 65536
}

// ---------------- norms + block-level scan of in-degree (fused) ----------------
__global__ void k_norm_scan(const int* __restrict__ dgO, const int* __restrict__ dgI,
                            float* __restrict__ nO, float* __restrict__ nI,
                            int* __restrict__ excl, int* __restrict__ blksum, int N) {
  __shared__ int s[256];
  int t = threadIdx.x;
  int n = blockIdx.x * 256 + t;
  int di = 0;
  if (n < N) {
    int o = dgO[n];
    di = dgI[n];
    nO[n] = rsqrtf((float)(o > 1 ? o : 1));
    nI[n] = rsqrtf((float)(di > 1 ? di : 1));
  }
  s[t] = di;
  __syncthreads();
  for (int o = 1; o < 256; o <<= 1) {
    int x = (t >= o) ? s[t - o] : 0;
    __syncthreads();
    s[t] += x;
    __syncthreads();
  }
  if (n < N) excl[n] = s[t] - di;          // exclusive within block
  if (t == 255) blksum[blockIdx.x] = s[255];
}

// single-block exclusive scan of up to 4096 block sums (1024 thr x 4 serial)
__global__ void k_scan2(int* __restrict__ blksum, int nb) {
  __shared__ int s[1024];
  int t = threadIdx.x;
  int base = t * 4;
  int v0 = base + 0 < nb ? blksum[base + 0] : 0;
  int v1 = base + 1 < nb ? blksum[base + 1] : 0;
  int v2 = base + 2 < nb ? blksum[base + 2] : 0;
  int v3 = base + 3 < nb ? blksum[base + 3] : 0;
  int sum = v0 + v1 + v2 + v3;
  s[t] = sum;
  __syncthreads();
  for (int o = 1; o < 1024; o <<= 1) {
    int x = (t >= o) ? s[t - o] : 0;
    __syncthreads();
    s[t] += x;
    __syncthreads();
  }
  int excl = s[t] - sum;
  if (base + 0 < nb) blksum[base + 0] = excl;
  if (base + 1 < nb) blksum[base + 1] = excl + v0;
  if (base + 2 < nb) blksum[base + 2] = excl + v0 + v1;
  if (base + 3 < nb) blksum[base + 3] = excl + v0 + v1 + v2;
}

// bucket-fill, NO atomics; block-scan offset folded in (blks[d>>8], 1.6KB L1-hot)
__global__ void k_fill(const int* __restrict__ src, const int* __restrict__ dst,
                       const unsigned short* __restrict__ gt,
                       const int* __restrict__ offs, const int* __restrict__ blks,
                       int* __restrict__ csr, int E) {
  int e = blockIdx.x * 256 + threadIdx.x;
  if (e >= E) return;
  int d = dst[e];
  csr[offs[d] + blks[d >> 8] + gt[e]] = src[e];
}

// ---------------- embedding gather, pre-scaled by norm_out ----------------
__global__ void k_embed(const int* __restrict__ feat, const float* __restrict__ emb,
                        const float* __restrict__ nO, float* __restrict__ h, int N) {
  int t = blockIdx.x * 256 + threadIdx.x;
  int n = t >> 4, q = t & 15;
  if (n >= N) return;
  float4 v = *(const float4*)(emb + (size_t)feat[n] * HID + q * 4);
  float s = nO[n];
  v.x *= s; v.y *= s; v.z *= s; v.w *= s;
  *(float4*)(h + (size_t)n * HID + q * 4) = v;
}

// ---------------- fused gather + linear ----------------
// Per block: 64 nodes. Phase A: 4 lanes/node gather sum(hs[src]) (64B/lane)
// into LDS x-tile scaled by nI. Phase B: lane j holds W[:,j] in 64 VGPRs
// (loaded once from LDS, conflict-free); inner loop = broadcast b128 xs reads
// + FMA only -> phase-B LDS traffic cut ~60x vs per-node Ws re-reads.
__global__ __launch_bounds__(256) void k_gl(
    const float* __restrict__ hs, const int* __restrict__ csr,
    const int* __restrict__ offs, const int* __restrict__ blks,
    const int* __restrict__ deg, const float* __restrict__ nI,
    const float* __restrict__ W, const float* __restrict__ b,
    float* __restrict__ out, int N, const float* __restrict__ postscale) {
  __shared__ float Ws[HID * HID];        // 16 KB
  __shared__ float xs[LIN_NODES * HID];  // 16 KB
  int t = threadIdx.x;
  for (int i = t * 4; i < HID * HID; i += 256 * 4)
    *(float4*)(Ws + i) = *(const float4*)(W + i);

  int n0 = blockIdx.x * LIN_NODES;
  int gnode = t >> 2, q = t & 3;         // 64 nodes x 4 lanes; lane q = cols q*16..+15
  int n = n0 + gnode;
  float4 a0 = make_float4(0.f, 0.f, 0.f, 0.f), a1 = a0, a2 = a0, a3 = a0;
  if (n < N) {
    int r0 = offs[n] + blks[n >> 8];
    int d = deg[n];
    const float* hq = hs + q * 16;
    int i = 0;
    for (; i + 1 < d; i += 2) {
      int s0 = csr[r0 + i], s1 = csr[r0 + i + 1];
      const float* p0 = hq + (size_t)s0 * HID;
      const float* p1 = hq + (size_t)s1 * HID;
      float4 v0 = *(const float4*)(p0);
      float4 v1 = *(const float4*)(p0 + 4);
      float4 v2 = *(const float4*)(p0 + 8);
      float4 v3 = *(const float4*)(p0 + 12);
      float4 w0 = *(const float4*)(p1);
      float4 w1 = *(const float4*)(p1 + 4);
      float4 w2 = *(const float4*)(p1 + 8);
      float4 w3 = *(const float4*)(p1 + 12);
      a0.x += v0.x + w0.x; a0.y += v0.y + w0.y; a0.z += v0.z + w0.z; a0.w += v0.w + w0.w;
      a1.x += v1.x + w1.x; a1.y += v1.y + w1.y; a1.z += v1.z + w1.z; a1.w += v1.w + w1.w;
      a2.x += v2.x + w2.x; a2.y += v2.y + w2.y; a2.z += v2.z + w2.z; a2.w += v2.w + w2.w;
      a3.x += v3.x + w3.x; a3.y += v3.y + w3.y; a3.z += v3.z + w3.z; a3.w += v3.w + w3.w;
    }
    if (i < d) {
      int s0 = csr[r0 + i];
      const float* p0 = hq + (size_t)s0 * HID;
      float4 v0 = *(const float4*)(p0);
      float4 v1 = *(const float4*)(p0 + 4);
      float4 v2 = *(const float4*)(p0 + 8);
      float4 v3 = *(const float4*)(p0 + 12);
      a0.x += v0.x; a0.y += v0.y; a0.z += v0.z; a0.w += v0.w;
      a1.x += v1.x; a1.y += v1.y; a1.z += v1.z; a1.w += v1.w;
      a2.x += v2.x; a2.y += v2.y; a2.z += v2.z; a2.w += v2.w;
      a3.x += v3.x; a3.y += v3.y; a3.z += v3.z; a3.w += v3.w;
    }
    float sc = nI[n];
    a0.x *= sc; a0.y *= sc; a0.z *= sc; a0.w *= sc;
    a1.x *= sc; a1.y *= sc; a1.z *= sc; a1.w *= sc;
    a2.x *= sc; a2.y *= sc; a2.z *= sc; a2.w *= sc;
    a3.x *= sc; a3.y *= sc; a3.z *= sc; a3.w *= sc;
  }
  float* xp = xs + gnode * HID + q * 16;
  *(float4*)(xp) = a0;
  *(float4*)(xp + 4) = a1;
  *(float4*)(xp + 8) = a2;
  *(float4*)(xp + 12) = a3;
  __syncthreads();

  int j = t & 63, rg = t >> 6;  // 4 waves, each handles 16 nodes; lane j = out col
  // lane j's W column -> registers (once). For fixed k, lanes read consecutive
  // floats: conflict-free. All indices static after unroll (no scratch).
  float4 wc[16];
#pragma unroll
  for (int k4 = 0; k4 < 16; ++k4)
    wc[k4] = make_float4(Ws[(4 * k4 + 0) * HID + j], Ws[(4 * k4 + 1) * HID + j],
                         Ws[(4 * k4 + 2) * HID + j], Ws[(4 * k4 + 3) * HID + j]);
  float bj = b[j];
  for (int r = 0; r < LIN_NODES / 4; ++r) {
    int node = rg * (LIN_NODES / 4) + r;
    float acc = bj;
    const float* xr = xs + node * HID;
#pragma unroll
    for (int k4 = 0; k4 < 16; ++k4) {
      float4 x4 = *(const float4*)(xr + k4 * 4);   // same-addr broadcast read
      acc = fmaf(x4.x, wc[k4].x, acc);
      acc = fmaf(x4.y, wc[k4].y, acc);
      acc = fmaf(x4.z, wc[k4].z, acc);
      acc = fmaf(x4.w, wc[k4].w, acc);
    }
    int nn = n0 + node;
    if (nn < N) {
      float ps = postscale ? postscale[nn] : 1.f;
      out[(size_t)nn * HID + j] = fmaxf(acc, 0.f) * ps;
    }
  }
}

// ---------------- per-graph sum + count (gid sorted -> run-length, wave-uniform) ----
__global__ __launch_bounds__(256) void k_pool(
    const float* __restrict__ h, const int* __restrict__ gid,
    float* __restrict__ sums, int* __restrict__ cnt, int N) {
  int t = threadIdx.x;
  int j = t & 63, sub = t >> 6;
  int base = blockIdx.x * 256 + sub * 64;
  int cur = -1, rl = 0;
  float acc = 0.f;
  for (int i = 0; i < 64; ++i) {
    int n = base + i;
    if (n >= N) break;
    int g = gid[n];
    float v = h[(size_t)n * HID + j];
    if (g != cur) {
      if (cur >= 0) {
        unsafeAtomicAdd(&sums[cur * HID + j], acc);
        if (j == 0) atomicAdd(&cnt[cur], rl);
      }
      cur = g; acc = v; rl = 1;
    } else {
      acc += v; ++rl;
    }
  }
  if (cur >= 0) {
    unsafeAtomicAdd(&sums[cur * HID + j], acc);
    if (j == 0) atomicAdd(&cnt[cur], rl);
  }
}

// ---------------- mean ----------------
__global__ void k_div(const float* __restrict__ sums, const int* __restrict__ cnt,
                      float* __restrict__ out) {
  int i = blockIdx.x * 256 + threadIdx.x;
  if (i >= NGRAPHS * HID) return;
  float c = (float)cnt[i >> 6];
  out[i] = sums[i] / fmaxf(c, 1.f);
}

extern "C" void kernel_launch(void* const* d_in, const int* in_sizes, int n_in,
                              void* d_out, int out_size, void* d_ws, size_t ws_size,
                              hipStream_t stream) {
  const int* node_feat = (const int*)d_in[0];
  const int* src = (const int*)d_in[1];
  const int* dst = (const int*)d_in[2];
  const int* gid = (const int*)d_in[3];
  const float* emb = (const float*)d_in[4];
  const float* W[3] = {(const float*)d_in[5], (const float*)d_in[7], (const float*)d_in[9]};
  const float* b[3] = {(const float*)d_in[6], (const float*)d_in[8], (const float*)d_in[10]};
  float* out = (float*)d_out;
  int N = in_sizes[0];
  int E = in_sizes[1];
  int nblk = (N + 255) / 256;  // 391 for N=100000

  char* ws = (char*)d_ws;
  size_t off_b = 0;
  auto alloc = [&](size_t bytes) {
    char* p = ws + off_b;
    off_b = (off_b + bytes + 255) & ~(size_t)255;
    return p;
  };
  // All zero-init buffers first; ONE memset covers the whole span (padding incl).
  int* dgO = (int*)alloc((size_t)2 * N * 4);   // dgO | dgI contiguous
  int* dgI = dgO + N;
  float* sums = (float*)alloc(NGRAPHS * HID * 4);
  int* cnt = (int*)alloc(NGRAPHS * 4);
  size_t zero_span = off_b;                     // bytes from ws start to zero
  float* nO = (float*)alloc((size_t)N * 4);
  float* nI = (float*)alloc((size_t)N * 4);
  int* offs = (int*)alloc((size_t)N * 4);
  int* blks = (int*)alloc(4096 * 4);
  unsigned short* gt = (unsigned short*)alloc((size_t)E * 2);
  int* csr = (int*)alloc((size_t)E * 4);
  float* h0 = (float*)alloc((size_t)N * HID * 4);
  float* h1 = (float*)alloc((size_t)N * HID * 4);

  hipMemsetAsync(ws, 0, zero_span, stream);

  // degrees + tickets
  k_deg<<<(E + 255) / 256, 256, 0, stream>>>(src, dst, dgO, dgI, gt, E);
  // norms + scan level 1 (fused), then block-sum scan; fill folds blks add
  k_norm_scan<<<nblk, 256, 0, stream>>>(dgO, dgI, nO, nI, offs, blks, N);
  k_scan2<<<1, 1024, 0, stream>>>(blks, nblk);
  k_fill<<<(E + 255) / 256, 256, 0, stream>>>(src, dst, gt, offs, blks, csr, E);

  // h0 = emb[feat] * nO
  k_embed<<<((size_t)N * 16 + 255) / 256, 256, 0, stream>>>(node_feat, emb, nO, h0, N);

  // fused gather+linear, ping-pong h0 <-> h1
  int nblkG = (N + LIN_NODES - 1) / LIN_NODES;
  k_gl<<<nblkG, 256, 0, stream>>>(h0, csr, offs, blks, dgI, nI, W[0], b[0], h1, N, nO);
  k_gl<<<nblkG, 256, 0, stream>>>(h1, csr, offs, blks, dgI, nI, W[1], b[1], h0, N, nO);
  k_gl<<<nblkG, 256, 0, stream>>>(h0, csr, offs, blks, dgI, nI, W[2], b[2], h1, N, nullptr);

  k_pool<<<nblk, 256, 0, stream>>>(h1, gid, sums, cnt, N);
  k_div<<<(NGRAPHS * HID + 255) / 256, 256, 0, stream>>>(sums, cnt, out);
}

// Round 10
// 383.513 us; speedup vs baseline: 1.2483x; 1.2483x over previous
//
#include <hip/hip_runtime.h>

#define HID 64
#define NGRAPHS 64
#define LIN_NODES 64

// ---- bf16 helpers (RTNE pack, bit-shift unpack) ----
__device__ __forceinline__ unsigned rtne16(float f) {
  unsigned u = __float_as_uint(f);
  return (u + 0x7FFFu + ((u >> 16) & 1u)) >> 16;
}
__device__ __forceinline__ unsigned packbf(float a, float b) {
  return rtne16(a) | (rtne16(b) << 16);
}
__device__ __forceinline__ float blo(unsigned w) { return __uint_as_float(w << 16); }
__device__ __forceinline__ float bhi(unsigned w) { return __uint_as_float(w & 0xFFFF0000u); }

// ---------------- degree count + ticket ----------------
// Plain device-scope atomics (R3: spreading null; R4: XCD-scope negative ->
// ~26G/s memory-side floor). In-degree atomic's return value = edge's slot
// within its dst node -> k_fill needs no atomics.
__global__ void k_deg(const int* __restrict__ src, const int* __restrict__ dst,
                      int* __restrict__ dgO, int* __restrict__ dgI,
                      unsigned short* __restrict__ gt, int E) {
  int e = blockIdx.x * 256 + threadIdx.x;
  if (e >= E) return;
  atomicAdd(&dgO[src[e]], 1);
  int t = atomicAdd(&dgI[dst[e]], 1);
  gt[e] = (unsigned short)t;
}

// ---------------- norms + block-level scan of in-degree (fused) ----------------
__global__ void k_norm_scan(const int* __restrict__ dgO, const int* __restrict__ dgI,
                            float* __restrict__ nO, float* __restrict__ nI,
                            int* __restrict__ excl, int* __restrict__ blksum, int N) {
  __shared__ int s[256];
  int t = threadIdx.x;
  int n = blockIdx.x * 256 + t;
  int di = 0;
  if (n < N) {
    int o = dgO[n];
    di = dgI[n];
    nO[n] = rsqrtf((float)(o > 1 ? o : 1));
    nI[n] = rsqrtf((float)(di > 1 ? di : 1));
  }
  s[t] = di;
  __syncthreads();
  for (int o = 1; o < 256; o <<= 1) {
    int x = (t >= o) ? s[t - o] : 0;
    __syncthreads();
    s[t] += x;
    __syncthreads();
  }
  if (n < N) excl[n] = s[t] - di;
  if (t == 255) blksum[blockIdx.x] = s[255];
}

// single-block exclusive scan of up to 4096 block sums
__global__ void k_scan2(int* __restrict__ blksum, int nb) {
  __shared__ int s[1024];
  int t = threadIdx.x;
  int base = t * 4;
  int v0 = base + 0 < nb ? blksum[base + 0] : 0;
  int v1 = base + 1 < nb ? blksum[base + 1] : 0;
  int v2 = base + 2 < nb ? blksum[base + 2] : 0;
  int v3 = base + 3 < nb ? blksum[base + 3] : 0;
  int sum = v0 + v1 + v2 + v3;
  s[t] = sum;
  __syncthreads();
  for (int o = 1; o < 1024; o <<= 1) {
    int x = (t >= o) ? s[t - o] : 0;
    __syncthreads();
    s[t] += x;
    __syncthreads();
  }
  int excl = s[t] - sum;
  if (base + 0 < nb) blksum[base + 0] = excl;
  if (base + 1 < nb) blksum[base + 1] = excl + v0;
  if (base + 2 < nb) blksum[base + 2] = excl + v0 + v1;
  if (base + 3 < nb) blksum[base + 3] = excl + v0 + v1 + v2;
}

// bucket-fill, NO atomics; block-scan offset folded in
__global__ void k_fill(const int* __restrict__ src, const int* __restrict__ dst,
                       const unsigned short* __restrict__ gt,
                       const int* __restrict__ offs, const int* __restrict__ blks,
                       int* __restrict__ csr, int E) {
  int e = blockIdx.x * 256 + threadIdx.x;
  if (e >= E) return;
  int d = dst[e];
  csr[offs[d] + blks[d >> 8] + gt[e]] = src[e];
}

// ---------------- embedding gather, pre-scaled by norm_out, bf16 out ----------
__global__ void k_embed(const int* __restrict__ feat, const float* __restrict__ emb,
                        const float* __restrict__ nO, unsigned short* __restrict__ h,
                        int N) {
  int t = blockIdx.x * 256 + threadIdx.x;
  int n = t >> 4, q = t & 15;
  if (n >= N) return;
  float4 v = *(const float4*)(emb + (size_t)feat[n] * HID + q * 4);
  float s = nO[n];
  uint2 o;
  o.x = packbf(v.x * s, v.y * s);
  o.y = packbf(v.z * s, v.w * s);
  *(uint2*)(h + (size_t)n * HID + q * 4) = o;
}

// ---------------- fused gather + linear, bf16 h in ----------------
// Phase A: 4 lanes/node, each lane 2 uint4 (16 bf16) per src row; fp32 accumulate.
// Phase B: lane j holds W[:,j] in regs; broadcast xs reads + FMA.
// LAST=false: out bf16 (relu * postscale nO);  LAST=true: out fp32 raw relu.
template <bool LAST>
__global__ __launch_bounds__(256) void k_gl(
    const unsigned short* __restrict__ hs, const int* __restrict__ csr,
    const int* __restrict__ offs, const int* __restrict__ blks,
    const int* __restrict__ deg, const float* __restrict__ nI,
    const float* __restrict__ W, const float* __restrict__ b,
    unsigned short* __restrict__ outb, float* __restrict__ outf,
    int N, const float* __restrict__ postscale) {
  __shared__ float Ws[HID * HID];        // 16 KB
  __shared__ float xs[LIN_NODES * HID];  // 16 KB
  int t = threadIdx.x;
  for (int i = t * 4; i < HID * HID; i += 256 * 4)
    *(float4*)(Ws + i) = *(const float4*)(W + i);

  int n0 = blockIdx.x * LIN_NODES;
  int gnode = t >> 2, q = t & 3;         // 64 nodes x 4 lanes; lane q = cols q*16..+15
  int n = n0 + gnode;
  float4 a0 = make_float4(0.f, 0.f, 0.f, 0.f), a1 = a0, a2 = a0, a3 = a0;
  if (n < N) {
    int r0 = offs[n] + blks[n >> 8];
    int d = deg[n];
    int i = 0;
    for (; i + 1 < d; i += 2) {
      int s0 = csr[r0 + i], s1 = csr[r0 + i + 1];
      const uint4* p0 = (const uint4*)(hs + (size_t)s0 * HID) + q * 2;
      const uint4* p1 = (const uint4*)(hs + (size_t)s1 * HID) + q * 2;
      uint4 u0 = p0[0], u1 = p0[1];
      uint4 w0 = p1[0], w1 = p1[1];
      a0.x += blo(u0.x) + blo(w0.x); a0.y += bhi(u0.x) + bhi(w0.x);
      a0.z += blo(u0.y) + blo(w0.y); a0.w += bhi(u0.y) + bhi(w0.y);
      a1.x += blo(u0.z) + blo(w0.z); a1.y += bhi(u0.z) + bhi(w0.z);
      a1.z += blo(u0.w) + blo(w0.w); a1.w += bhi(u0.w) + bhi(w0.w);
      a2.x += blo(u1.x) + blo(w1.x); a2.y += bhi(u1.x) + bhi(w1.x);
      a2.z += blo(u1.y) + blo(w1.y); a2.w += bhi(u1.y) + bhi(w1.y);
      a3.x += blo(u1.z) + blo(w1.z); a3.y += bhi(u1.z) + bhi(w1.z);
      a3.z += blo(u1.w) + blo(w1.w); a3.w += bhi(u1.w) + bhi(w1.w);
    }
    if (i < d) {
      int s0 = csr[r0 + i];
      const uint4* p0 = (const uint4*)(hs + (size_t)s0 * HID) + q * 2;
      uint4 u0 = p0[0], u1 = p0[1];
      a0.x += blo(u0.x); a0.y += bhi(u0.x); a0.z += blo(u0.y); a0.w += bhi(u0.y);
      a1.x += blo(u0.z); a1.y += bhi(u0.z); a1.z += blo(u0.w); a1.w += bhi(u0.w);
      a2.x += blo(u1.x); a2.y += bhi(u1.x); a2.z += blo(u1.y); a2.w += bhi(u1.y);
      a3.x += blo(u1.z); a3.y += bhi(u1.z); a3.z += blo(u1.w); a3.w += bhi(u1.w);
    }
    float sc = nI[n];
    a0.x *= sc; a0.y *= sc; a0.z *= sc; a0.w *= sc;
    a1.x *= sc; a1.y *= sc; a1.z *= sc; a1.w *= sc;
    a2.x *= sc; a2.y *= sc; a2.z *= sc; a2.w *= sc;
    a3.x *= sc; a3.y *= sc; a3.z *= sc; a3.w *= sc;
  }
  float* xp = xs + gnode * HID + q * 16;
  *(float4*)(xp) = a0;
  *(float4*)(xp + 4) = a1;
  *(float4*)(xp + 8) = a2;
  *(float4*)(xp + 12) = a3;
  __syncthreads();

  int j = t & 63, rg = t >> 6;  // 4 waves x 16 nodes; lane j = output col
  float4 wc[16];
#pragma unroll
  for (int k4 = 0; k4 < 16; ++k4)
    wc[k4] = make_float4(Ws[(4 * k4 + 0) * HID + j], Ws[(4 * k4 + 1) * HID + j],
                         Ws[(4 * k4 + 2) * HID + j], Ws[(4 * k4 + 3) * HID + j]);
  float bj = b[j];
  for (int r = 0; r < LIN_NODES / 4; ++r) {
    int node = rg * (LIN_NODES / 4) + r;
    float acc = bj;
    const float* xr = xs + node * HID;
#pragma unroll
    for (int k4 = 0; k4 < 16; ++k4) {
      float4 x4 = *(const float4*)(xr + k4 * 4);
      acc = fmaf(x4.x, wc[k4].x, acc);
      acc = fmaf(x4.y, wc[k4].y, acc);
      acc = fmaf(x4.z, wc[k4].z, acc);
      acc = fmaf(x4.w, wc[k4].w, acc);
    }
    int nn = n0 + node;
    if (LAST) {
      if (nn < N) outf[(size_t)nn * HID + j] = fmaxf(acc, 0.f);
    } else {
      float val = fmaxf(acc, 0.f) * postscale[nn < N ? nn : 0];
      float other = __shfl_xor(val, 1);   // all lanes participate
      if (nn < N && (j & 1) == 0)
        *(unsigned*)(outb + (size_t)nn * HID + j) = packbf(val, other);
    }
  }
}

// ---------------- per-graph sum + count (gid sorted -> run-length) ----------------
__global__ __launch_bounds__(256) void k_pool(
    const float* __restrict__ h, const int* __restrict__ gid,
    float* __restrict__ sums, int* __restrict__ cnt, int N) {
  int t = threadIdx.x;
  int j = t & 63, sub = t >> 6;
  int base = blockIdx.x * 256 + sub * 64;
  int cur = -1, rl = 0;
  float acc = 0.f;
  for (int i = 0; i < 64; ++i) {
    int n = base + i;
    if (n >= N) break;
    int g = gid[n];
    float v = h[(size_t)n * HID + j];
    if (g != cur) {
      if (cur >= 0) {
        unsafeAtomicAdd(&sums[cur * HID + j], acc);
        if (j == 0) atomicAdd(&cnt[cur], rl);
      }
      cur = g; acc = v; rl = 1;
    } else {
      acc += v; ++rl;
    }
  }
  if (cur >= 0) {
    unsafeAtomicAdd(&sums[cur * HID + j], acc);
    if (j == 0) atomicAdd(&cnt[cur], rl);
  }
}

// ---------------- mean ----------------
__global__ void k_div(const float* __restrict__ sums, const int* __restrict__ cnt,
                      float* __restrict__ out) {
  int i = blockIdx.x * 256 + threadIdx.x;
  if (i >= NGRAPHS * HID) return;
  float c = (float)cnt[i >> 6];
  out[i] = sums[i] / fmaxf(c, 1.f);
}

extern "C" void kernel_launch(void* const* d_in, const int* in_sizes, int n_in,
                              void* d_out, int out_size, void* d_ws, size_t ws_size,
                              hipStream_t stream) {
  const int* node_feat = (const int*)d_in[0];
  const int* src = (const int*)d_in[1];
  const int* dst = (const int*)d_in[2];
  const int* gid = (const int*)d_in[3];
  const float* emb = (const float*)d_in[4];
  const float* W[3] = {(const float*)d_in[5], (const float*)d_in[7], (const float*)d_in[9]};
  const float* b[3] = {(const float*)d_in[6], (const float*)d_in[8], (const float*)d_in[10]};
  float* out = (float*)d_out;
  int N = in_sizes[0];
  int E = in_sizes[1];
  int nblk = (N + 255) / 256;  // 391 for N=100000

  char* ws = (char*)d_ws;
  size_t off_b = 0;
  auto alloc = [&](size_t bytes) {
    char* p = ws + off_b;
    off_b = (off_b + bytes + 255) & ~(size_t)255;
    return p;
  };
  // Zero-init buffers first; ONE memset covers the whole span.
  int* dgO = (int*)alloc((size_t)2 * N * 4);   // dgO | dgI contiguous
  int* dgI = dgO + N;
  float* sums = (float*)alloc(NGRAPHS * HID * 4);
  int* cnt = (int*)alloc(NGRAPHS * 4);
  size_t zero_span = off_b;
  float* nO = (float*)alloc((size_t)N * 4);
  float* nI = (float*)alloc((size_t)N * 4);
  int* offs = (int*)alloc((size_t)N * 4);
  int* blks = (int*)alloc(4096 * 4);
  unsigned short* gt = (unsigned short*)alloc((size_t)E * 2);
  int* csr = (int*)alloc((size_t)E * 4);
  unsigned short* hb0 = (unsigned short*)alloc((size_t)N * HID * 2);  // bf16 h
  unsigned short* hb1 = (unsigned short*)alloc((size_t)N * HID * 2);  // bf16 h
  float* h3 = (float*)alloc((size_t)N * HID * 4);                    // fp32 last

  hipMemsetAsync(ws, 0, zero_span, stream);

  k_deg<<<(E + 255) / 256, 256, 0, stream>>>(src, dst, dgO, dgI, gt, E);
  k_norm_scan<<<nblk, 256, 0, stream>>>(dgO, dgI, nO, nI, offs, blks, N);
  k_scan2<<<1, 1024, 0, stream>>>(blks, nblk);
  k_fill<<<(E + 255) / 256, 256, 0, stream>>>(src, dst, gt, offs, blks, csr, E);

  k_embed<<<((size_t)N * 16 + 255) / 256, 256, 0, stream>>>(node_feat, emb, nO, hb0, N);

  int nblkG = (N + LIN_NODES - 1) / LIN_NODES;
  k_gl<false><<<nblkG, 256, 0, stream>>>(hb0, csr, offs, blks, dgI, nI, W[0], b[0],
                                         hb1, nullptr, N, nO);
  k_gl<false><<<nblkG, 256, 0, stream>>>(hb1, csr, offs, blks, dgI, nI, W[1], b[1],
                                         hb0, nullptr, N, nO);
  k_gl<true><<<nblkG, 256, 0, stream>>>(hb0, csr, offs, blks, dgI, nI, W[2], b[2],
                                        nullptr, h3, N, nullptr);

  k_pool<<<nblk, 256, 0, stream>>>(h3, gid, sums, cnt, N);
  k_div<<<(NGRAPHS * HID + 255) / 256, 256, 0, stream>>>(sums, cnt, out);
}

// Round 11
// 363.172 us; speedup vs baseline: 1.3183x; 1.0560x over previous
//
#include <hip/hip_runtime.h>

#define HID 64
#define NGRAPHS 64
#define LIN_NODES 64

// ---- bf16 helpers (RTNE pack, bit-shift unpack) ----
__device__ __forceinline__ unsigned rtne16(float f) {
  unsigned u = __float_as_uint(f);
  return (u + 0x7FFFu + ((u >> 16) & 1u)) >> 16;
}
__device__ __forceinline__ unsigned packbf(float a, float b) {
  return rtne16(a) | (rtne16(b) << 16);
}
__device__ __forceinline__ float blo(unsigned w) { return __uint_as_float(w << 16); }
__device__ __forceinline__ float bhi(unsigned w) { return __uint_as_float(w & 0xFFFF0000u); }

// ---------------- degree count + ticket ----------------
// Device-scope atomics: ~26G random-line RMW/s is the measured floor (R3
// spreading null, R4 XCD-scope negative). Ticket = in-degree atomic return.
__global__ void k_deg(const int* __restrict__ src, const int* __restrict__ dst,
                      int* __restrict__ dgO, int* __restrict__ dgI,
                      unsigned short* __restrict__ gt, int E) {
  int e = blockIdx.x * 256 + threadIdx.x;
  if (e >= E) return;
  atomicAdd(&dgO[src[e]], 1);
  int t = atomicAdd(&dgI[dst[e]], 1);
  gt[e] = (unsigned short)t;
}

// ---------------- norms + block-level scan of in-degree (fused) ----------------
__global__ void k_norm_scan(const int* __restrict__ dgO, const int* __restrict__ dgI,
                            float* __restrict__ nO, float* __restrict__ nI,
                            int* __restrict__ excl, int* __restrict__ blksum, int N) {
  __shared__ int s[256];
  int t = threadIdx.x;
  int n = blockIdx.x * 256 + t;
  int di = 0;
  if (n < N) {
    int o = dgO[n];
    di = dgI[n];
    nO[n] = rsqrtf((float)(o > 1 ? o : 1));
    nI[n] = rsqrtf((float)(di > 1 ? di : 1));
  }
  s[t] = di;
  __syncthreads();
  for (int o = 1; o < 256; o <<= 1) {
    int x = (t >= o) ? s[t - o] : 0;
    __syncthreads();
    s[t] += x;
    __syncthreads();
  }
  if (n < N) excl[n] = s[t] - di;
  if (t == 255) blksum[blockIdx.x] = s[255];
}

// single-block exclusive scan of up to 4096 block sums
__global__ void k_scan2(int* __restrict__ blksum, int nb) {
  __shared__ int s[1024];
  int t = threadIdx.x;
  int base = t * 4;
  int v0 = base + 0 < nb ? blksum[base + 0] : 0;
  int v1 = base + 1 < nb ? blksum[base + 1] : 0;
  int v2 = base + 2 < nb ? blksum[base + 2] : 0;
  int v3 = base + 3 < nb ? blksum[base + 3] : 0;
  int sum = v0 + v1 + v2 + v3;
  s[t] = sum;
  __syncthreads();
  for (int o = 1; o < 1024; o <<= 1) {
    int x = (t >= o) ? s[t - o] : 0;
    __syncthreads();
    s[t] += x;
    __syncthreads();
  }
  int excl = s[t] - sum;
  if (base + 0 < nb) blksum[base + 0] = excl;
  if (base + 1 < nb) blksum[base + 1] = excl + v0;
  if (base + 2 < nb) blksum[base + 2] = excl + v0 + v1;
  if (base + 3 < nb) blksum[base + 3] = excl + v0 + v1 + v2;
}

// ---------------- fused fill + embed + count (independent jobs, one dispatch) ----
// blocks [0, nbF): csr fill (no atomics, ticket-based)
// blocks [nbF, nbF+nbE): embedding gather pre-scaled by nO, bf16 out
// blocks [nbF+nbE, ...): per-graph node counts via LDS histogram
__global__ __launch_bounds__(256) void k_fused(
    const int* __restrict__ src, const int* __restrict__ dst,
    const unsigned short* __restrict__ gt, const int* __restrict__ offs,
    const int* __restrict__ blks, int* __restrict__ csr, int E,
    const int* __restrict__ feat, const float* __restrict__ emb,
    const float* __restrict__ nO, unsigned short* __restrict__ h,
    const int* __restrict__ gid, int* __restrict__ cnt, int N,
    int nbF, int nbE) {
  __shared__ int hh[NGRAPHS];
  int bid = blockIdx.x;
  if (bid < nbF) {
    int e = bid * 256 + threadIdx.x;
    if (e >= E) return;
    int d = dst[e];
    csr[offs[d] + blks[d >> 8] + gt[e]] = src[e];
  } else if (bid < nbF + nbE) {
    int t = (bid - nbF) * 256 + threadIdx.x;
    int n = t >> 4, q = t & 15;
    if (n >= N) return;
    float4 v = *(const float4*)(emb + (size_t)feat[n] * HID + q * 4);
    float s = nO[n];
    uint2 o;
    o.x = packbf(v.x * s, v.y * s);
    o.y = packbf(v.z * s, v.w * s);
    *(uint2*)(h + (size_t)n * HID + q * 4) = o;
  } else {
    int t = threadIdx.x;
    if (t < NGRAPHS) hh[t] = 0;
    __syncthreads();
    int n = (bid - nbF - nbE) * 256 + t;
    if (n < N) atomicAdd(&hh[gid[n]], 1);
    __syncthreads();
    if (t < NGRAPHS && hh[t]) atomicAdd(&cnt[t], hh[t]);
  }
}

// ---------------- fused gather + linear (+ pool epilogue on last layer) --------
// Phase A: 4 lanes/node gather bf16 rows, fp32 accumulate, scale by nI -> xs.
// Phase B: lane j holds W[:,j] in regs; broadcast xs reads + FMA.
// LAST=false: write bf16 h (relu * nO). LAST=true: stash relu vals back into
// xs (per-wave-disjoint rows, read-before-write in lockstep), then one wave
// run-length-pools the block's 64 sorted-gid nodes -> ~64 atomics/block.
template <bool LAST>
__global__ __launch_bounds__(256) void k_gl(
    const unsigned short* __restrict__ hs, const int* __restrict__ csr,
    const int* __restrict__ offs, const int* __restrict__ blks,
    const int* __restrict__ deg, const float* __restrict__ nI,
    const float* __restrict__ W, const float* __restrict__ b,
    unsigned short* __restrict__ outb, const int* __restrict__ gid,
    float* __restrict__ sums, int N, const float* __restrict__ postscale) {
  __shared__ float Ws[HID * HID];        // 16 KB
  __shared__ float xs[LIN_NODES * HID];  // 16 KB
  int t = threadIdx.x;
  for (int i = t * 4; i < HID * HID; i += 256 * 4)
    *(float4*)(Ws + i) = *(const float4*)(W + i);

  int n0 = blockIdx.x * LIN_NODES;
  int gnode = t >> 2, q = t & 3;         // 64 nodes x 4 lanes
  int n = n0 + gnode;
  float4 a0 = make_float4(0.f, 0.f, 0.f, 0.f), a1 = a0, a2 = a0, a3 = a0;
  if (n < N) {
    int r0 = offs[n] + blks[n >> 8];
    int d = deg[n];
    int i = 0;
    for (; i + 1 < d; i += 2) {
      int s0 = csr[r0 + i], s1 = csr[r0 + i + 1];
      const uint4* p0 = (const uint4*)(hs + (size_t)s0 * HID) + q * 2;
      const uint4* p1 = (const uint4*)(hs + (size_t)s1 * HID) + q * 2;
      uint4 u0 = p0[0], u1 = p0[1];
      uint4 w0 = p1[0], w1 = p1[1];
      a0.x += blo(u0.x) + blo(w0.x); a0.y += bhi(u0.x) + bhi(w0.x);
      a0.z += blo(u0.y) + blo(w0.y); a0.w += bhi(u0.y) + bhi(w0.y);
      a1.x += blo(u0.z) + blo(w0.z); a1.y += bhi(u0.z) + bhi(w0.z);
      a1.z += blo(u0.w) + blo(w0.w); a1.w += bhi(u0.w) + bhi(w0.w);
      a2.x += blo(u1.x) + blo(w1.x); a2.y += bhi(u1.x) + bhi(w1.x);
      a2.z += blo(u1.y) + blo(w1.y); a2.w += bhi(u1.y) + bhi(w1.y);
      a3.x += blo(u1.z) + blo(w1.z); a3.y += bhi(u1.z) + bhi(w1.z);
      a3.z += blo(u1.w) + blo(w1.w); a3.w += bhi(u1.w) + bhi(w1.w);
    }
    if (i < d) {
      int s0 = csr[r0 + i];
      const uint4* p0 = (const uint4*)(hs + (size_t)s0 * HID) + q * 2;
      uint4 u0 = p0[0], u1 = p0[1];
      a0.x += blo(u0.x); a0.y += bhi(u0.x); a0.z += blo(u0.y); a0.w += bhi(u0.y);
      a1.x += blo(u0.z); a1.y += bhi(u0.z); a1.z += blo(u0.w); a1.w += bhi(u0.w);
      a2.x += blo(u1.x); a2.y += bhi(u1.x); a2.z += blo(u1.y); a2.w += bhi(u1.y);
      a3.x += blo(u1.z); a3.y += bhi(u1.z); a3.z += blo(u1.w); a3.w += bhi(u1.w);
    }
    float sc = nI[n];
    a0.x *= sc; a0.y *= sc; a0.z *= sc; a0.w *= sc;
    a1.x *= sc; a1.y *= sc; a1.z *= sc; a1.w *= sc;
    a2.x *= sc; a2.y *= sc; a2.z *= sc; a2.w *= sc;
    a3.x *= sc; a3.y *= sc; a3.z *= sc; a3.w *= sc;
  }
  float* xp = xs + gnode * HID + q * 16;
  *(float4*)(xp) = a0;
  *(float4*)(xp + 4) = a1;
  *(float4*)(xp + 8) = a2;
  *(float4*)(xp + 12) = a3;
  __syncthreads();

  int j = t & 63, rg = t >> 6;  // 4 waves x 16 nodes; lane j = output col
  float4 wc[16];
#pragma unroll
  for (int k4 = 0; k4 < 16; ++k4)
    wc[k4] = make_float4(Ws[(4 * k4 + 0) * HID + j], Ws[(4 * k4 + 1) * HID + j],
                         Ws[(4 * k4 + 2) * HID + j], Ws[(4 * k4 + 3) * HID + j]);
  float bj = b[j];
  for (int r = 0; r < LIN_NODES / 4; ++r) {
    int node = rg * (LIN_NODES / 4) + r;
    float acc = bj;
    const float* xr = xs + node * HID;
#pragma unroll
    for (int k4 = 0; k4 < 16; ++k4) {
      float4 x4 = *(const float4*)(xr + k4 * 4);
      acc = fmaf(x4.x, wc[k4].x, acc);
      acc = fmaf(x4.y, wc[k4].y, acc);
      acc = fmaf(x4.z, wc[k4].z, acc);
      acc = fmaf(x4.w, wc[k4].w, acc);
    }
    int nn = n0 + node;
    if (LAST) {
      // stash relu val back into this wave's own xs row (reads done above;
      // waves own disjoint rows; in-wave lockstep orders read-before-write)
      if (nn < N) xs[node * HID + j] = fmaxf(acc, 0.f);
    } else {
      float val = fmaxf(acc, 0.f) * postscale[nn < N ? nn : 0];
      float other = __shfl_xor(val, 1);
      if (nn < N && (j & 1) == 0)
        *(unsigned*)(outb + (size_t)nn * HID + j) = packbf(val, other);
    }
  }
  if (LAST) {
    __syncthreads();
    if (t < 64) {  // one wave run-length-pools 64 sorted-gid nodes from LDS
      int cur = -1;
      float acc = 0.f;
      for (int i = 0; i < LIN_NODES; ++i) {
        int nn = n0 + i;
        if (nn >= N) break;
        int g = gid[nn];
        float v = xs[i * HID + t];
        if (g != cur) {
          if (cur >= 0) unsafeAtomicAdd(&sums[cur * HID + t], acc);
          cur = g; acc = v;
        } else {
          acc += v;
        }
      }
      if (cur >= 0) unsafeAtomicAdd(&sums[cur * HID + t], acc);
    }
  }
}

// ---------------- mean ----------------
__global__ void k_div(const float* __restrict__ sums, const int* __restrict__ cnt,
                      float* __restrict__ out) {
  int i = blockIdx.x * 256 + threadIdx.x;
  if (i >= NGRAPHS * HID) return;
  float c = (float)cnt[i >> 6];
  out[i] = sums[i] / fmaxf(c, 1.f);
}

extern "C" void kernel_launch(void* const* d_in, const int* in_sizes, int n_in,
                              void* d_out, int out_size, void* d_ws, size_t ws_size,
                              hipStream_t stream) {
  const int* node_feat = (const int*)d_in[0];
  const int* src = (const int*)d_in[1];
  const int* dst = (const int*)d_in[2];
  const int* gid = (const int*)d_in[3];
  const float* emb = (const float*)d_in[4];
  const float* W[3] = {(const float*)d_in[5], (const float*)d_in[7], (const float*)d_in[9]};
  const float* b[3] = {(const float*)d_in[6], (const float*)d_in[8], (const float*)d_in[10]};
  float* out = (float*)d_out;
  int N = in_sizes[0];
  int E = in_sizes[1];
  int nblk = (N + 255) / 256;  // 391 for N=100000

  char* ws = (char*)d_ws;
  size_t off_b = 0;
  auto alloc = [&](size_t bytes) {
    char* p = ws + off_b;
    off_b = (off_b + bytes + 255) & ~(size_t)255;
    return p;
  };
  // Zero-init buffers first; ONE memset covers the whole span.
  int* dgO = (int*)alloc((size_t)2 * N * 4);   // dgO | dgI contiguous
  int* dgI = dgO + N;
  float* sums = (float*)alloc(NGRAPHS * HID * 4);
  int* cnt = (int*)alloc(NGRAPHS * 4);
  size_t zero_span = off_b;
  float* nO = (float*)alloc((size_t)N * 4);
  float* nI = (float*)alloc((size_t)N * 4);
  int* offs = (int*)alloc((size_t)N * 4);
  int* blks = (int*)alloc(4096 * 4);
  unsigned short* gt = (unsigned short*)alloc((size_t)E * 2);
  int* csr = (int*)alloc((size_t)E * 4);
  unsigned short* hb0 = (unsigned short*)alloc((size_t)N * HID * 2);  // bf16 h
  unsigned short* hb1 = (unsigned short*)alloc((size_t)N * HID * 2);  // bf16 h

  hipMemsetAsync(ws, 0, zero_span, stream);

  k_deg<<<(E + 255) / 256, 256, 0, stream>>>(src, dst, dgO, dgI, gt, E);
  k_norm_scan<<<nblk, 256, 0, stream>>>(dgO, dgI, nO, nI, offs, blks, N);
  k_scan2<<<1, 1024, 0, stream>>>(blks, nblk);

  // fill + embed + count in one dispatch (all deps satisfied)
  int nbF = (E + 255) / 256;
  int nbE = ((int)((size_t)N * 16 + 255)) / 256;
  k_fused<<<nbF + nbE + nblk, 256, 0, stream>>>(
      src, dst, gt, offs, blks, csr, E,
      node_feat, emb, nO, hb0, gid, cnt, N, nbF, nbE);

  int nblkG = (N + LIN_NODES - 1) / LIN_NODES;
  k_gl<false><<<nblkG, 256, 0, stream>>>(hb0, csr, offs, blks, dgI, nI, W[0], b[0],
                                         hb1, nullptr, nullptr, N, nO);
  k_gl<false><<<nblkG, 256, 0, stream>>>(hb1, csr, offs, blks, dgI, nI, W[1], b[1],
                                         hb0, nullptr, nullptr, N, nO);
  k_gl<true><<<nblkG, 256, 0, stream>>>(hb0, csr, offs, blks, dgI, nI, W[2], b[2],
                                        nullptr, gid, sums, N, nullptr);

  k_div<<<(NGRAPHS * HID + 255) / 256, 256, 0, stream>>>(sums, cnt, out);
}

// Round 12
// 316.650 us; speedup vs baseline: 1.5119x; 1.1469x over previous
//
#include <hip/hip_runtime.h>

#define HID 64
#define NGRAPHS 64
#define LIN_NODES 64
#define EPB 8192        // edges per block in hist/scatter passes
#define BSH 9           // bucket shift: 512 nodes per bucket

// ---- bf16 helpers (RTNE pack, bit-shift unpack) ----
__device__ __forceinline__ unsigned rtne16(float f) {
  unsigned u = __float_as_uint(f);
  return (u + 0x7FFFu + ((u >> 16) & 1u)) >> 16;
}
__device__ __forceinline__ unsigned packbf(float a, float b) {
  return rtne16(a) | (rtne16(b) << 16);
}
__device__ __forceinline__ float blo(unsigned w) { return __uint_as_float(w << 16); }
__device__ __forceinline__ float bhi(unsigned w) { return __uint_as_float(w & 0xFFFF0000u); }

// ---------------- pass 1: per-(bucket,block) coarse histograms (LDS only) ------
// countsD/countsS layout: [bucket * KB + block] so bucket regions scan contiguous.
__global__ __launch_bounds__(256) void k_hist(
    const int* __restrict__ src, const int* __restrict__ dst,
    int* __restrict__ countsD, int* __restrict__ countsS,
    int E, int NB, int KB) {
  __shared__ int hD[256], hS[256];
  int t = threadIdx.x;
  hD[t] = 0; hS[t] = 0;
  __syncthreads();
  int e0 = blockIdx.x * EPB;
  for (int i = 0; i < EPB / 256; ++i) {
    int e = e0 + i * 256 + t;
    if (e < E) {
      atomicAdd(&hD[dst[e] >> BSH], 1);
      atomicAdd(&hS[src[e] >> BSH], 1);
    }
  }
  __syncthreads();
  if (t < NB) {
    countsD[t * KB + blockIdx.x] = hD[t];
    countsS[t * KB + blockIdx.x] = hS[t];
  }
}

// ---------------- pass 2: single-block exclusive scan of M ints, in place ------
// grid = 2 blocks: block 0 scans countsD, block 1 scans countsS.
__global__ __launch_bounds__(1024) void k_scanM(int* __restrict__ A0,
                                                int* __restrict__ A1, int M) {
  int* A = blockIdx.x == 0 ? A0 : A1;
  __shared__ int s[1024];
  int t = threadIdx.x;
  int CH = (M + 1023) >> 10;
  int base = t * CH;
  int sum = 0;
  for (int i = 0; i < CH; ++i) {
    int idx = base + i;
    if (idx < M) sum += A[idx];
  }
  s[t] = sum;
  __syncthreads();
  for (int o = 1; o < 1024; o <<= 1) {
    int x = (t >= o) ? s[t - o] : 0;
    __syncthreads();
    s[t] += x;
    __syncthreads();
  }
  int run = s[t] - sum;   // exclusive base for this thread's chunk
  for (int i = 0; i < CH; ++i) {
    int idx = base + i;
    if (idx < M) {
      int v = A[idx];
      A[idx] = run;
      run += v;
    }
  }
}

// ---------------- pass 3: scatter edges into bucket-grouped buffers ------------
// bufD word = src | (dstLow << 17)  (src < 2^17, dstLow 9 bits)
// bufS word = src & 511 (ushort) for the out-degree side.
__global__ __launch_bounds__(256) void k_scat(
    const int* __restrict__ src, const int* __restrict__ dst,
    const int* __restrict__ exclD, const int* __restrict__ exclS,
    unsigned* __restrict__ bufD, unsigned short* __restrict__ bufS,
    int E, int NB, int KB) {
  __shared__ int cD[256], cS[256];
  int t = threadIdx.x;
  if (t < NB) {
    cD[t] = exclD[t * KB + blockIdx.x];
    cS[t] = exclS[t * KB + blockIdx.x];
  }
  __syncthreads();
  int e0 = blockIdx.x * EPB;
  for (int i = 0; i < EPB / 256; ++i) {
    int e = e0 + i * 256 + t;
    if (e < E) {
      int s = src[e], d = dst[e];
      int pd = atomicAdd(&cD[d >> BSH], 1);
      bufD[pd] = (unsigned)s | ((unsigned)(d & 511) << 17);
      int ps = atomicAdd(&cS[s >> BSH], 1);
      bufS[ps] = (unsigned short)(s & 511);
    }
  }
}

// ---------------- pass 4: per-bucket fine histogram -> deg/offs/norm/csr -------
// grid = 2*NB blocks. bid < NB: dst side (deg, offs, nI, csr scatter).
//                    bid >= NB: src side (nO only).
__global__ __launch_bounds__(256) void k_csrB(
    const unsigned* __restrict__ bufD, const unsigned short* __restrict__ bufS,
    const int* __restrict__ exclD, const int* __restrict__ exclS,
    int* __restrict__ csr, int* __restrict__ deg, int* __restrict__ offs,
    float* __restrict__ nI, float* __restrict__ nO,
    int E, int N, int NB, int KB) {
  __shared__ int hist[512], loc[512];
  int t = threadIdx.x;
  hist[t] = 0; hist[t + 256] = 0;
  __syncthreads();
  int bid = blockIdx.x;
  if (bid < NB) {
    int beg = exclD[bid * KB];
    int end = (bid + 1 < NB) ? exclD[(bid + 1) * KB] : E;
    for (int i = beg + t; i < end; i += 256)
      atomicAdd(&hist[(bufD[i] >> 17) & 511], 1);
    __syncthreads();
    if (t == 0) {
      int run = 0;
      for (int i = 0; i < 512; ++i) { loc[i] = run; run += hist[i]; }
    }
    __syncthreads();
#pragma unroll
    for (int k = 0; k < 2; ++k) {
      int bin = t + k * 256;
      int n = (bid << BSH) + bin;
      if (n < N) {
        int dgv = hist[bin];
        deg[n] = dgv;
        offs[n] = beg + loc[bin];
        nI[n] = rsqrtf((float)(dgv > 1 ? dgv : 1));
      }
    }
    __syncthreads();
    for (int i = beg + t; i < end; i += 256) {
      unsigned w = bufD[i];
      int r = atomicAdd(&loc[(w >> 17) & 511], 1);   // starts at excl offset
      csr[beg + r] = (int)(w & 0x1FFFFu);
    }
  } else {
    int b = bid - NB;
    int beg = exclS[b * KB];
    int end = (b + 1 < NB) ? exclS[(b + 1) * KB] : E;
    for (int i = beg + t; i < end; i += 256)
      atomicAdd(&hist[bufS[i]], 1);
    __syncthreads();
#pragma unroll
    for (int k = 0; k < 2; ++k) {
      int bin = t + k * 256;
      int n = (b << BSH) + bin;
      if (n < N) {
        int dgv = hist[bin];
        nO[n] = rsqrtf((float)(dgv > 1 ? dgv : 1));
      }
    }
  }
}

// ---------------- fused embed + count (independent jobs, one dispatch) ---------
__global__ __launch_bounds__(256) void k_fused(
    const int* __restrict__ feat, const float* __restrict__ emb,
    const float* __restrict__ nO, unsigned short* __restrict__ h,
    const int* __restrict__ gid, int* __restrict__ cnt, int N, int nbE) {
  __shared__ int hh[NGRAPHS];
  int bid = blockIdx.x;
  if (bid < nbE) {
    int t = bid * 256 + threadIdx.x;
    int n = t >> 4, q = t & 15;
    if (n >= N) return;
    float4 v = *(const float4*)(emb + (size_t)feat[n] * HID + q * 4);
    float s = nO[n];
    uint2 o;
    o.x = packbf(v.x * s, v.y * s);
    o.y = packbf(v.z * s, v.w * s);
    *(uint2*)(h + (size_t)n * HID + q * 4) = o;
  } else {
    int t = threadIdx.x;
    if (t < NGRAPHS) hh[t] = 0;
    __syncthreads();
    int n = (bid - nbE) * 256 + t;
    if (n < N) atomicAdd(&hh[gid[n]], 1);
    __syncthreads();
    if (t < NGRAPHS && hh[t]) atomicAdd(&cnt[t], hh[t]);
  }
}

// ---------------- fused gather + linear (+ pool epilogue on last layer) --------
template <bool LAST>
__global__ __launch_bounds__(256) void k_gl(
    const unsigned short* __restrict__ hs, const int* __restrict__ csr,
    const int* __restrict__ offs, const int* __restrict__ deg,
    const float* __restrict__ nI, const float* __restrict__ W,
    const float* __restrict__ b, unsigned short* __restrict__ outb,
    const int* __restrict__ gid, float* __restrict__ sums,
    int N, const float* __restrict__ postscale) {
  __shared__ float Ws[HID * HID];        // 16 KB
  __shared__ float xs[LIN_NODES * HID];  // 16 KB
  int t = threadIdx.x;
  for (int i = t * 4; i < HID * HID; i += 256 * 4)
    *(float4*)(Ws + i) = *(const float4*)(W + i);

  int n0 = blockIdx.x * LIN_NODES;
  int gnode = t >> 2, q = t & 3;         // 64 nodes x 4 lanes
  int n = n0 + gnode;
  float4 a0 = make_float4(0.f, 0.f, 0.f, 0.f), a1 = a0, a2 = a0, a3 = a0;
  if (n < N) {
    int r0 = offs[n];
    int d = deg[n];
    int i = 0;
    for (; i + 1 < d; i += 2) {
      int s0 = csr[r0 + i], s1 = csr[r0 + i + 1];
      const uint4* p0 = (const uint4*)(hs + (size_t)s0 * HID) + q * 2;
      const uint4* p1 = (const uint4*)(hs + (size_t)s1 * HID) + q * 2;
      uint4 u0 = p0[0], u1 = p0[1];
      uint4 w0 = p1[0], w1 = p1[1];
      a0.x += blo(u0.x) + blo(w0.x); a0.y += bhi(u0.x) + bhi(w0.x);
      a0.z += blo(u0.y) + blo(w0.y); a0.w += bhi(u0.y) + bhi(w0.y);
      a1.x += blo(u0.z) + blo(w0.z); a1.y += bhi(u0.z) + bhi(w0.z);
      a1.z += blo(u0.w) + blo(w0.w); a1.w += bhi(u0.w) + bhi(w0.w);
      a2.x += blo(u1.x) + blo(w1.x); a2.y += bhi(u1.x) + bhi(w1.x);
      a2.z += blo(u1.y) + blo(w1.y); a2.w += bhi(u1.y) + bhi(w1.y);
      a3.x += blo(u1.z) + blo(w1.z); a3.y += bhi(u1.z) + bhi(w1.z);
      a3.z += blo(u1.w) + blo(w1.w); a3.w += bhi(u1.w) + bhi(w1.w);
    }
    if (i < d) {
      int s0 = csr[r0 + i];
      const uint4* p0 = (const uint4*)(hs + (size_t)s0 * HID) + q * 2;
      uint4 u0 = p0[0], u1 = p0[1];
      a0.x += blo(u0.x); a0.y += bhi(u0.x); a0.z += blo(u0.y); a0.w += bhi(u0.y);
      a1.x += blo(u0.z); a1.y += bhi(u0.z); a1.z += blo(u0.w); a1.w += bhi(u0.w);
      a2.x += blo(u1.x); a2.y += bhi(u1.x); a2.z += blo(u1.y); a2.w += bhi(u1.y);
      a3.x += blo(u1.z); a3.y += bhi(u1.z); a3.z += blo(u1.w); a3.w += bhi(u1.w);
    }
    float sc = nI[n];
    a0.x *= sc; a0.y *= sc; a0.z *= sc; a0.w *= sc;
    a1.x *= sc; a1.y *= sc; a1.z *= sc; a1.w *= sc;
    a2.x *= sc; a2.y *= sc; a2.z *= sc; a2.w *= sc;
    a3.x *= sc; a3.y *= sc; a3.z *= sc; a3.w *= sc;
  }
  float* xp = xs + gnode * HID + q * 16;
  *(float4*)(xp) = a0;
  *(float4*)(xp + 4) = a1;
  *(float4*)(xp + 8) = a2;
  *(float4*)(xp + 12) = a3;
  __syncthreads();

  int j = t & 63, rg = t >> 6;  // 4 waves x 16 nodes; lane j = output col
  float4 wc[16];
#pragma unroll
  for (int k4 = 0; k4 < 16; ++k4)
    wc[k4] = make_float4(Ws[(4 * k4 + 0) * HID + j], Ws[(4 * k4 + 1) * HID + j],
                         Ws[(4 * k4 + 2) * HID + j], Ws[(4 * k4 + 3) * HID + j]);
  float bj = b[j];
  for (int r = 0; r < LIN_NODES / 4; ++r) {
    int node = rg * (LIN_NODES / 4) + r;
    float acc = bj;
    const float* xr = xs + node * HID;
#pragma unroll
    for (int k4 = 0; k4 < 16; ++k4) {
      float4 x4 = *(const float4*)(xr + k4 * 4);
      acc = fmaf(x4.x, wc[k4].x, acc);
      acc = fmaf(x4.y, wc[k4].y, acc);
      acc = fmaf(x4.z, wc[k4].z, acc);
      acc = fmaf(x4.w, wc[k4].w, acc);
    }
    int nn = n0 + node;
    if (LAST) {
      if (nn < N) xs[node * HID + j] = fmaxf(acc, 0.f);
    } else {
      float val = fmaxf(acc, 0.f) * postscale[nn < N ? nn : 0];
      float other = __shfl_xor(val, 1);
      if (nn < N && (j & 1) == 0)
        *(unsigned*)(outb + (size_t)nn * HID + j) = packbf(val, other);
    }
  }
  if (LAST) {
    __syncthreads();
    if (t < 64) {  // one wave run-length-pools 64 sorted-gid nodes from LDS
      int cur = -1;
      float acc = 0.f;
      for (int i = 0; i < LIN_NODES; ++i) {
        int nn = n0 + i;
        if (nn >= N) break;
        int g = gid[nn];
        float v = xs[i * HID + t];
        if (g != cur) {
          if (cur >= 0) unsafeAtomicAdd(&sums[cur * HID + t], acc);
          cur = g; acc = v;
        } else {
          acc += v;
        }
      }
      if (cur >= 0) unsafeAtomicAdd(&sums[cur * HID + t], acc);
    }
  }
}

// ---------------- mean ----------------
__global__ void k_div(const float* __restrict__ sums, const int* __restrict__ cnt,
                      float* __restrict__ out) {
  int i = blockIdx.x * 256 + threadIdx.x;
  if (i >= NGRAPHS * HID) return;
  float c = (float)cnt[i >> 6];
  out[i] = sums[i] / fmaxf(c, 1.f);
}

extern "C" void kernel_launch(void* const* d_in, const int* in_sizes, int n_in,
                              void* d_out, int out_size, void* d_ws, size_t ws_size,
                              hipStream_t stream) {
  const int* node_feat = (const int*)d_in[0];
  const int* src = (const int*)d_in[1];
  const int* dst = (const int*)d_in[2];
  const int* gid = (const int*)d_in[3];
  const float* emb = (const float*)d_in[4];
  const float* W[3] = {(const float*)d_in[5], (const float*)d_in[7], (const float*)d_in[9]};
  const float* b[3] = {(const float*)d_in[6], (const float*)d_in[8], (const float*)d_in[10]};
  float* out = (float*)d_out;
  int N = in_sizes[0];
  int E = in_sizes[1];
  int NB = (N + 511) >> BSH;          // 196 coarse buckets (512 nodes each)
  int KB = (E + EPB - 1) / EPB;       // 196 edge blocks
  int MD = NB * KB;                   // counts matrix size

  char* ws = (char*)d_ws;
  size_t off_b = 0;
  auto alloc = [&](size_t bytes) {
    char* p = ws + off_b;
    off_b = (off_b + bytes + 255) & ~(size_t)255;
    return p;
  };
  // Zero-init buffers first; ONE memset covers the whole span.
  float* sums = (float*)alloc(NGRAPHS * HID * 4);
  int* cnt = (int*)alloc(NGRAPHS * 4);
  size_t zero_span = off_b;
  int* countsD = (int*)alloc((size_t)MD * 4);
  int* countsS = (int*)alloc((size_t)MD * 4);
  unsigned* bufD = (unsigned*)alloc((size_t)E * 4);
  unsigned short* bufS = (unsigned short*)alloc((size_t)E * 2);
  int* csr = (int*)alloc((size_t)E * 4);
  int* deg = (int*)alloc((size_t)N * 4);
  int* offs = (int*)alloc((size_t)N * 4);
  float* nI = (float*)alloc((size_t)N * 4);
  float* nO = (float*)alloc((size_t)N * 4);
  unsigned short* hb0 = (unsigned short*)alloc((size_t)N * HID * 2);  // bf16 h
  unsigned short* hb1 = (unsigned short*)alloc((size_t)N * HID * 2);  // bf16 h

  hipMemsetAsync(ws, 0, zero_span, stream);

  // counting-sort CSR build: zero global atomics (LDS atomics only)
  k_hist<<<KB, 256, 0, stream>>>(src, dst, countsD, countsS, E, NB, KB);
  k_scanM<<<2, 1024, 0, stream>>>(countsD, countsS, MD);
  k_scat<<<KB, 256, 0, stream>>>(src, dst, countsD, countsS, bufD, bufS, E, NB, KB);
  k_csrB<<<2 * NB, 256, 0, stream>>>(bufD, bufS, countsD, countsS, csr, deg, offs,
                                     nI, nO, E, N, NB, KB);

  // embed + per-graph count in one dispatch
  int nbE = N / 16 + 1;
  int nblk = (N + 255) / 256;
  k_fused<<<nbE + nblk, 256, 0, stream>>>(node_feat, emb, nO, hb0, gid, cnt, N, nbE);

  int nblkG = (N + LIN_NODES - 1) / LIN_NODES;
  k_gl<false><<<nblkG, 256, 0, stream>>>(hb0, csr, offs, deg, nI, W[0], b[0],
                                         hb1, nullptr, nullptr, N, nO);
  k_gl<false><<<nblkG, 256, 0, stream>>>(hb1, csr, offs, deg, nI, W[1], b[1],
                                         hb0, nullptr, nullptr, N, nO);
  k_gl<true><<<nblkG, 256, 0, stream>>>(hb0, csr, offs, deg, nI, W[2], b[2],
                                        nullptr, gid, sums, N, nullptr);

  k_div<<<(NGRAPHS * HID + 255) / 256, 256, 0, stream>>>(sums, cnt, out);
}

// Round 13
// 256.463 us; speedup vs baseline: 1.8668x; 1.2347x over previous
//
#include <hip/hip_runtime.h>

#define HID 64
#define NGRAPHS 64
#define LIN_NODES 64
#define EPB 8192        // edges per block in hist/scatter passes
#define BSH 9           // bucket shift: 512 nodes per bucket

// ---- bf16 helpers (RTNE pack, bit-shift unpack) ----
__device__ __forceinline__ unsigned rtne16(float f) {
  unsigned u = __float_as_uint(f);
  return (u + 0x7FFFu + ((u >> 16) & 1u)) >> 16;
}
__device__ __forceinline__ unsigned packbf(float a, float b) {
  return rtne16(a) | (rtne16(b) << 16);
}
__device__ __forceinline__ float blo(unsigned w) { return __uint_as_float(w << 16); }
__device__ __forceinline__ float bhi(unsigned w) { return __uint_as_float(w & 0xFFFF0000u); }

// ---------------- pass 1: per-(bucket,block) coarse histograms (LDS only) ------
__global__ __launch_bounds__(256) void k_hist(
    const int* __restrict__ src, const int* __restrict__ dst,
    int* __restrict__ countsD, int* __restrict__ countsS,
    int E, int NB, int KB) {
  __shared__ int hD[256], hS[256];
  int t = threadIdx.x;
  hD[t] = 0; hS[t] = 0;
  __syncthreads();
  int e0 = blockIdx.x * EPB;
  for (int i = 0; i < EPB / 256; ++i) {
    int e = e0 + i * 256 + t;
    if (e < E) {
      atomicAdd(&hD[dst[e] >> BSH], 1);
      atomicAdd(&hS[src[e] >> BSH], 1);
    }
  }
  __syncthreads();
  if (t < NB) {
    countsD[t * KB + blockIdx.x] = hD[t];
    countsS[t * KB + blockIdx.x] = hS[t];
  }
}

// ---------------- pass 2a: per-row exclusive scan (one block per bucket row) ---
// grid = 2*NB. bid<NB: countsD row bid; else countsS row bid-NB.
// rows[bid] = row total (scanned exclusively by k_scanB).
__global__ __launch_bounds__(256) void k_scanA(
    int* __restrict__ A0, int* __restrict__ A1, int* __restrict__ rows,
    int NB, int KB) {
  int bid = blockIdx.x;
  int* A = (bid < NB) ? A0 : A1;
  int row = (bid < NB) ? bid : bid - NB;
  __shared__ int s[256];
  int t = threadIdx.x;
  int base = row * KB + t * 4;
  int v0 = (t * 4 + 0 < KB) ? A[base + 0] : 0;
  int v1 = (t * 4 + 1 < KB) ? A[base + 1] : 0;
  int v2 = (t * 4 + 2 < KB) ? A[base + 2] : 0;
  int v3 = (t * 4 + 3 < KB) ? A[base + 3] : 0;
  int sum = v0 + v1 + v2 + v3;
  s[t] = sum;
  __syncthreads();
  for (int o = 1; o < 256; o <<= 1) {
    int x = (t >= o) ? s[t - o] : 0;
    __syncthreads();
    s[t] += x;
    __syncthreads();
  }
  int excl = s[t] - sum;
  if (t * 4 + 0 < KB) A[base + 0] = excl;
  if (t * 4 + 1 < KB) A[base + 1] = excl + v0;
  if (t * 4 + 2 < KB) A[base + 2] = excl + v0 + v1;
  if (t * 4 + 3 < KB) A[base + 3] = excl + v0 + v1 + v2;
  if (t == 255) rows[bid] = s[255];
}

// ---------------- pass 2b: exclusive scan of row totals (2 arrays) -------------
__global__ __launch_bounds__(256) void k_scanB(int* __restrict__ rows, int NB) {
  __shared__ int s[256];
  int t = threadIdx.x;
  int* R = rows + blockIdx.x * NB;
  int v = (t < NB) ? R[t] : 0;
  s[t] = v;
  __syncthreads();
  for (int o = 1; o < 256; o <<= 1) {
    int x = (t >= o) ? s[t - o] : 0;
    __syncthreads();
    s[t] += x;
    __syncthreads();
  }
  if (t < NB) R[t] = s[t] - v;
}

// ---------------- pass 3: scatter edges into bucket-grouped buffers ------------
// bufD word = src | (dstLow << 17); bufS = src & 511.
__global__ __launch_bounds__(256) void k_scat(
    const int* __restrict__ src, const int* __restrict__ dst,
    const int* __restrict__ exclD, const int* __restrict__ exclS,
    const int* __restrict__ rows,
    unsigned* __restrict__ bufD, unsigned short* __restrict__ bufS,
    int E, int NB, int KB) {
  __shared__ int cD[256], cS[256];
  int t = threadIdx.x;
  if (t < NB) {
    cD[t] = exclD[t * KB + blockIdx.x] + rows[t];
    cS[t] = exclS[t * KB + blockIdx.x] + rows[NB + t];
  }
  __syncthreads();
  int e0 = blockIdx.x * EPB;
  for (int i = 0; i < EPB / 256; ++i) {
    int e = e0 + i * 256 + t;
    if (e < E) {
      int s = src[e], d = dst[e];
      int pd = atomicAdd(&cD[d >> BSH], 1);
      bufD[pd] = (unsigned)s | ((unsigned)(d & 511) << 17);
      int ps = atomicAdd(&cS[s >> BSH], 1);
      bufS[ps] = (unsigned short)(s & 511);
    }
  }
}

// ---------------- pass 4: per-bucket fine histogram -> deg/offs/norm/csr -------
__global__ __launch_bounds__(256) void k_csrB(
    const unsigned* __restrict__ bufD, const unsigned short* __restrict__ bufS,
    const int* __restrict__ exclD, const int* __restrict__ exclS,
    const int* __restrict__ rows,
    int* __restrict__ csr, int* __restrict__ deg, int* __restrict__ offs,
    float* __restrict__ nI, float* __restrict__ nO,
    int E, int N, int NB, int KB) {
  __shared__ int hist[512], loc[512];
  int t = threadIdx.x;
  hist[t] = 0; hist[t + 256] = 0;
  __syncthreads();
  int bid = blockIdx.x;
  if (bid < NB) {
    int beg = exclD[bid * KB] + rows[bid];
    int end = (bid + 1 < NB) ? exclD[(bid + 1) * KB] + rows[bid + 1] : E;
    for (int i = beg + t; i < end; i += 256)
      atomicAdd(&hist[(bufD[i] >> 17) & 511], 1);
    __syncthreads();
    if (t == 0) {
      int run = 0;
      for (int i = 0; i < 512; ++i) { loc[i] = run; run += hist[i]; }
    }
    __syncthreads();
#pragma unroll
    for (int k = 0; k < 2; ++k) {
      int bin = t + k * 256;
      int n = (bid << BSH) + bin;
      if (n < N) {
        int dgv = hist[bin];
        deg[n] = dgv;
        offs[n] = beg + loc[bin];
        nI[n] = rsqrtf((float)(dgv > 1 ? dgv : 1));
      }
    }
    __syncthreads();
    for (int i = beg + t; i < end; i += 256) {
      unsigned w = bufD[i];
      int r = atomicAdd(&loc[(w >> 17) & 511], 1);
      csr[beg + r] = (int)(w & 0x1FFFFu);
    }
  } else {
    int b = bid - NB;
    int beg = exclS[b * KB] + rows[NB + b];
    int end = (b + 1 < NB) ? exclS[(b + 1) * KB] + rows[NB + b + 1] : E;
    for (int i = beg + t; i < end; i += 256)
      atomicAdd(&hist[bufS[i]], 1);
    __syncthreads();
#pragma unroll
    for (int k = 0; k < 2; ++k) {
      int bin = t + k * 256;
      int n = (b << BSH) + bin;
      if (n < N) {
        int dgv = hist[bin];
        nO[n] = rsqrtf((float)(dgv > 1 ? dgv : 1));
      }
    }
  }
}

// ---------------- fused embed + count (independent jobs, one dispatch) ---------
__global__ __launch_bounds__(256) void k_fused(
    const int* __restrict__ feat, const float* __restrict__ emb,
    const float* __restrict__ nO, unsigned short* __restrict__ h,
    const int* __restrict__ gid, int* __restrict__ cnt, int N, int nbE) {
  __shared__ int hh[NGRAPHS];
  int bid = blockIdx.x;
  if (bid < nbE) {
    int t = bid * 256 + threadIdx.x;
    int n = t >> 4, q = t & 15;
    if (n >= N) return;
    float4 v = *(const float4*)(emb + (size_t)feat[n] * HID + q * 4);
    float s = nO[n];
    uint2 o;
    o.x = packbf(v.x * s, v.y * s);
    o.y = packbf(v.z * s, v.w * s);
    *(uint2*)(h + (size_t)n * HID + q * 4) = o;
  } else {
    int t = threadIdx.x;
    if (t < NGRAPHS) hh[t] = 0;
    __syncthreads();
    int n = (bid - nbE) * 256 + t;
    if (n < N) atomicAdd(&hh[gid[n]], 1);
    __syncthreads();
    if (t < NGRAPHS && hh[t]) atomicAdd(&cnt[t], hh[t]);
  }
}

// ---------------- fused gather + linear (+ pool epilogue on last layer) --------
template <bool LAST>
__global__ __launch_bounds__(256) void k_gl(
    const unsigned short* __restrict__ hs, const int* __restrict__ csr,
    const int* __restrict__ offs, const int* __restrict__ deg,
    const float* __restrict__ nI, const float* __restrict__ W,
    const float* __restrict__ b, unsigned short* __restrict__ outb,
    const int* __restrict__ gid, float* __restrict__ sums,
    int N, const float* __restrict__ postscale) {
  __shared__ float Ws[HID * HID];        // 16 KB
  __shared__ float xs[LIN_NODES * HID];  // 16 KB
  int t = threadIdx.x;
  for (int i = t * 4; i < HID * HID; i += 256 * 4)
    *(float4*)(Ws + i) = *(const float4*)(W + i);

  int n0 = blockIdx.x * LIN_NODES;
  int gnode = t >> 2, q = t & 3;         // 64 nodes x 4 lanes
  int n = n0 + gnode;
  float4 a0 = make_float4(0.f, 0.f, 0.f, 0.f), a1 = a0, a2 = a0, a3 = a0;
  if (n < N) {
    int r0 = offs[n];
    int d = deg[n];
    int i = 0;
    for (; i + 1 < d; i += 2) {
      int s0 = csr[r0 + i], s1 = csr[r0 + i + 1];
      const uint4* p0 = (const uint4*)(hs + (size_t)s0 * HID) + q * 2;
      const uint4* p1 = (const uint4*)(hs + (size_t)s1 * HID) + q * 2;
      uint4 u0 = p0[0], u1 = p0[1];
      uint4 w0 = p1[0], w1 = p1[1];
      a0.x += blo(u0.x) + blo(w0.x); a0.y += bhi(u0.x) + bhi(w0.x);
      a0.z += blo(u0.y) + blo(w0.y); a0.w += bhi(u0.y) + bhi(w0.y);
      a1.x += blo(u0.z) + blo(w0.z); a1.y += bhi(u0.z) + bhi(w0.z);
      a1.z += blo(u0.w) + blo(w0.w); a1.w += bhi(u0.w) + bhi(w0.w);
      a2.x += blo(u1.x) + blo(w1.x); a2.y += bhi(u1.x) + bhi(w1.x);
      a2.z += blo(u1.y) + blo(w1.y); a2.w += bhi(u1.y) + bhi(w1.y);
      a3.x += blo(u1.z) + blo(w1.z); a3.y += bhi(u1.z) + bhi(w1.z);
      a3.z += blo(u1.w) + blo(w1.w); a3.w += bhi(u1.w) + bhi(w1.w);
    }
    if (i < d) {
      int s0 = csr[r0 + i];
      const uint4* p0 = (const uint4*)(hs + (size_t)s0 * HID) + q * 2;
      uint4 u0 = p0[0], u1 = p0[1];
      a0.x += blo(u0.x); a0.y += bhi(u0.x); a0.z += blo(u0.y); a0.w += bhi(u0.y);
      a1.x += blo(u0.z); a1.y += bhi(u0.z); a1.z += blo(u0.w); a1.w += bhi(u0.w);
      a2.x += blo(u1.x); a2.y += bhi(u1.x); a2.z += blo(u1.y); a2.w += bhi(u1.y);
      a3.x += blo(u1.z); a3.y += bhi(u1.z); a3.z += blo(u1.w); a3.w += bhi(u1.w);
    }
    float sc = nI[n];
    a0.x *= sc; a0.y *= sc; a0.z *= sc; a0.w *= sc;
    a1.x *= sc; a1.y *= sc; a1.z *= sc; a1.w *= sc;
    a2.x *= sc; a2.y *= sc; a2.z *= sc; a2.w *= sc;
    a3.x *= sc; a3.y *= sc; a3.z *= sc; a3.w *= sc;
  }
  float* xp = xs + gnode * HID + q * 16;
  *(float4*)(xp) = a0;
  *(float4*)(xp + 4) = a1;
  *(float4*)(xp + 8) = a2;
  *(float4*)(xp + 12) = a3;
  __syncthreads();

  int j = t & 63, rg = t >> 6;  // 4 waves x 16 nodes; lane j = output col
  float4 wc[16];
#pragma unroll
  for (int k4 = 0; k4 < 16; ++k4)
    wc[k4] = make_float4(Ws[(4 * k4 + 0) * HID + j], Ws[(4 * k4 + 1) * HID + j],
                         Ws[(4 * k4 + 2) * HID + j], Ws[(4 * k4 + 3) * HID + j]);
  float bj = b[j];
  for (int r = 0; r < LIN_NODES / 4; ++r) {
    int node = rg * (LIN_NODES / 4) + r;
    float acc = bj;
    const float* xr = xs + node * HID;
#pragma unroll
    for (int k4 = 0; k4 < 16; ++k4) {
      float4 x4 = *(const float4*)(xr + k4 * 4);
      acc = fmaf(x4.x, wc[k4].x, acc);
      acc = fmaf(x4.y, wc[k4].y, acc);
      acc = fmaf(x4.z, wc[k4].z, acc);
      acc = fmaf(x4.w, wc[k4].w, acc);
    }
    int nn = n0 + node;
    if (LAST) {
      if (nn < N) xs[node * HID + j] = fmaxf(acc, 0.f);
    } else {
      float val = fmaxf(acc, 0.f) * postscale[nn < N ? nn : 0];
      float other = __shfl_xor(val, 1);
      if (nn < N && (j & 1) == 0)
        *(unsigned*)(outb + (size_t)nn * HID + j) = packbf(val, other);
    }
  }
  if (LAST) {
    __syncthreads();
    if (t < 64) {  // one wave run-length-pools 64 sorted-gid nodes from LDS
      int cur = -1;
      float acc = 0.f;
      for (int i = 0; i < LIN_NODES; ++i) {
        int nn = n0 + i;
        if (nn >= N) break;
        int g = gid[nn];
        float v = xs[i * HID + t];
        if (g != cur) {
          if (cur >= 0) unsafeAtomicAdd(&sums[cur * HID + t], acc);
          cur = g; acc = v;
        } else {
          acc += v;
        }
      }
      if (cur >= 0) unsafeAtomicAdd(&sums[cur * HID + t], acc);
    }
  }
}

// ---------------- mean ----------------
__global__ void k_div(const float* __restrict__ sums, const int* __restrict__ cnt,
                      float* __restrict__ out) {
  int i = blockIdx.x * 256 + threadIdx.x;
  if (i >= NGRAPHS * HID) return;
  float c = (float)cnt[i >> 6];
  out[i] = sums[i] / fmaxf(c, 1.f);
}

extern "C" void kernel_launch(void* const* d_in, const int* in_sizes, int n_in,
                              void* d_out, int out_size, void* d_ws, size_t ws_size,
                              hipStream_t stream) {
  const int* node_feat = (const int*)d_in[0];
  const int* src = (const int*)d_in[1];
  const int* dst = (const int*)d_in[2];
  const int* gid = (const int*)d_in[3];
  const float* emb = (const float*)d_in[4];
  const float* W[3] = {(const float*)d_in[5], (const float*)d_in[7], (const float*)d_in[9]};
  const float* b[3] = {(const float*)d_in[6], (const float*)d_in[8], (const float*)d_in[10]};
  float* out = (float*)d_out;
  int N = in_sizes[0];
  int E = in_sizes[1];
  int NB = (N + 511) >> BSH;          // 196 coarse buckets (512 nodes each)
  int KB = (E + EPB - 1) / EPB;       // 196 edge blocks
  int MD = NB * KB;

  char* ws = (char*)d_ws;
  size_t off_b = 0;
  auto alloc = [&](size_t bytes) {
    char* p = ws + off_b;
    off_b = (off_b + bytes + 255) & ~(size_t)255;
    return p;
  };
  // Zero-init buffers first; ONE memset covers the whole span.
  float* sums = (float*)alloc(NGRAPHS * HID * 4);
  int* cnt = (int*)alloc(NGRAPHS * 4);
  size_t zero_span = off_b;
  int* countsD = (int*)alloc((size_t)MD * 4);
  int* countsS = (int*)alloc((size_t)MD * 4);
  int* rows = (int*)alloc((size_t)2 * NB * 4);   // row totals -> row bases
  unsigned* bufD = (unsigned*)alloc((size_t)E * 4);
  unsigned short* bufS = (unsigned short*)alloc((size_t)E * 2);
  int* csr = (int*)alloc((size_t)E * 4);
  int* deg = (int*)alloc((size_t)N * 4);
  int* offs = (int*)alloc((size_t)N * 4);
  float* nI = (float*)alloc((size_t)N * 4);
  float* nO = (float*)alloc((size_t)N * 4);
  unsigned short* hb0 = (unsigned short*)alloc((size_t)N * HID * 2);  // bf16 h
  unsigned short* hb1 = (unsigned short*)alloc((size_t)N * HID * 2);  // bf16 h

  hipMemsetAsync(ws, 0, zero_span, stream);

  // counting-sort CSR build: zero global atomics (LDS atomics only)
  k_hist<<<KB, 256, 0, stream>>>(src, dst, countsD, countsS, E, NB, KB);
  k_scanA<<<2 * NB, 256, 0, stream>>>(countsD, countsS, rows, NB, KB);
  k_scanB<<<2, 256, 0, stream>>>(rows, NB);
  k_scat<<<KB, 256, 0, stream>>>(src, dst, countsD, countsS, rows, bufD, bufS, E, NB, KB);
  k_csrB<<<2 * NB, 256, 0, stream>>>(bufD, bufS, countsD, countsS, rows, csr, deg,
                                     offs, nI, nO, E, N, NB, KB);

  // embed + per-graph count in one dispatch
  int nbE = N / 16 + 1;
  int nblk = (N + 255) / 256;
  k_fused<<<nbE + nblk, 256, 0, stream>>>(node_feat, emb, nO, hb0, gid, cnt, N, nbE);

  int nblkG = (N + LIN_NODES - 1) / LIN_NODES;
  k_gl<false><<<nblkG, 256, 0, stream>>>(hb0, csr, offs, deg, nI, W[0], b[0],
                                         hb1, nullptr, nullptr, N, nO);
  k_gl<false><<<nblkG, 256, 0, stream>>>(hb1, csr, offs, deg, nI, W[1], b[1],
                                         hb0, nullptr, nullptr, N, nO);
  k_gl<true><<<nblkG, 256, 0, stream>>>(hb0, csr, offs, deg, nI, W[2], b[2],
                                        nullptr, gid, sums, N, nullptr);

  k_div<<<(NGRAPHS * HID + 255) / 256, 256, 0, stream>>>(sums, cnt, out);
}